// Round 4
// baseline (75.666 us; speedup 1.0000x reference)
//
#include <hip/hip_runtime.h>

// ROIAlign (FPN, multi-level) for MI355X.
// Inputs (f32): fm2 [4,256,256,256] s4 | fm3 [4,128,128,256] s8
//               fm4 [4,64,64,256] s16  | fm5 [4,32,32,256] s32
//               rois [4,512,4] (x1,y1,x2,y2)
// Output (f32): [4,512,256,7,7]
//
// R3 -> R4: full-channel blocks. One block per ROI, 512 threads (8 waves);
// lane carries 4 channels so a wave-load is one full 1KB contiguous pixel
// (single coalesced transaction). Halves gather instruction count and runs
// the prologue/LUT once per ROI instead of twice. launch_bounds(512,4)
// gives VGPR<=128 so all 16 corner loads of a bin stay in flight.

constexpr int S     = 7;
constexpr int SS    = 49;
constexpr int CCH   = 256;
constexpr int NROI  = 512;
constexpr int BATCH = 4;
constexpr int CPAD  = 260;   // floats per bin row in LDS (256 + 4 pad)

__global__ __launch_bounds__(512, 4) void roialign_kernel(
    const float* __restrict__ fm2, const float* __restrict__ fm3,
    const float* __restrict__ fm4, const float* __restrict__ fm5,
    const float* __restrict__ rois, float* __restrict__ out)
{
    __shared__ float    tile[SS * CPAD];            // 50960 B
    __shared__ float    s_wyh[14], s_wyl[14], s_wxh[14], s_wxl[14];
    __shared__ unsigned s_ry0[14], s_ry1[14], s_cx0[14], s_cx1[14];

    const int roi = blockIdx.x;        // 0 .. B*N-1
    const int b   = roi >> 9;

    // ---- wave-uniform prologue ----
    const float x1  = rois[roi * 4 + 0];
    const float y1v = rois[roi * 4 + 1];
    const float x2  = rois[roi * 4 + 2];
    const float y2v = rois[roi * 4 + 3];

    const float area = (y2v - y1v) * (x2 - x1);
    const float lraw = logf(sqrtf(area) * (1.0f / 224.0f)) * 1.4426950408889634f + 4.0f;
    int lvl = (int)rintf(lraw);
    lvl = lvl < 2 ? 2 : (lvl > 5 ? 5 : lvl);

    const float* fm; int H; float scale;
    if (lvl == 2)      { fm = fm2; H = 256; scale = 0.25f;    }
    else if (lvl == 3) { fm = fm3; H = 128; scale = 0.125f;   }
    else if (lvl == 4) { fm = fm4; H = 64;  scale = 0.0625f;  }
    else               { fm = fm5; H = 32;  scale = 0.03125f; }
    const int W = H;
    fm += (size_t)b * H * W * CCH;

    const float bx1 = x1 * scale, by1 = y1v * scale;
    const float rw  = fmaxf(x2 * scale - bx1, 1.0f);
    const float rh  = fmaxf(y2v * scale - by1, 1.0f);
    const float stx = rw * (1.0f / 7.0f);
    const float sty = rh * (1.0f / 7.0f);

    const int t = threadIdx.x;

    // ---- sample LUT: 14 y entries (wave 0) + 14 x entries (wave 1) ----
    if (t < 14) {
        const int k = t;
        const float yy = by1 + ((float)k + 0.5f) * 0.5f * sty;
        const float Hf = (float)H;
        const bool  v  = (yy > -1.0f) && (yy < Hf);
        const float yc = fminf(fmaxf(yy, 0.0f), Hf - 1.0f);
        const int   y0 = (int)floorf(yc);
        const int   y1i = min(y0 + 1, H - 1);
        const float ly = yc - (float)y0;
        s_wyl[k] = v ? ly : 0.0f;
        s_wyh[k] = v ? 1.0f - ly : 0.0f;
        s_ry0[k] = (unsigned)(y0  * W * (CCH * 4));   // byte offset of fm row
        s_ry1[k] = (unsigned)(y1i * W * (CCH * 4));
    } else if (t >= 64 && t < 78) {
        const int k = t - 64;
        const float xx = bx1 + ((float)k + 0.5f) * 0.5f * stx;
        const float Wf = (float)W;
        const bool  v  = (xx > -1.0f) && (xx < Wf);
        const float xc = fminf(fmaxf(xx, 0.0f), Wf - 1.0f);
        const int   x0 = (int)floorf(xc);
        const int   x1i = min(x0 + 1, W - 1);
        const float lx = xc - (float)x0;
        s_wxl[k] = v ? lx : 0.0f;
        s_wxh[k] = v ? 1.0f - lx : 0.0f;
        s_cx0[k] = (unsigned)(x0  * (CCH * 4));       // byte offset of fm col
        s_cx1[k] = (unsigned)(x1i * (CCH * 4));
    }
    __syncthreads();

    // ---- compute: one bin per wave-pass, 4 channels (float4) per lane ----
    const int lane = t & 63;
    const int wv   = t >> 6;                       // 0..7
    const unsigned cb = (unsigned)(lane << 4);     // byte offset within pixel

    const char* __restrict__ fmb = (const char*)fm;   // block-uniform -> SGPR base

    for (int bin = wv; bin < SS; bin += 8) {
        const int sy = bin / 7;
        const int sx = bin - sy * 7;
        const int ky = sy << 1, kx = sx << 1;

        const float hy0 = s_wyh[ky],     ly0 = s_wyl[ky];
        const float hy1 = s_wyh[ky + 1], ly1 = s_wyl[ky + 1];
        const float hx0 = s_wxh[kx],     lx0 = s_wxl[kx];
        const float hx1 = s_wxh[kx + 1], lx1 = s_wxl[kx + 1];
        const unsigned rA = s_ry0[ky],     rB = s_ry1[ky];      // y-sample 0 rows
        const unsigned rC = s_ry0[ky + 1], rD = s_ry1[ky + 1];  // y-sample 1 rows
        const unsigned cA = s_cx0[kx],     cB = s_cx1[kx];      // x-sample 0 cols
        const unsigned cC = s_cx0[kx + 1], cD = s_cx1[kx + 1];  // x-sample 1 cols

        float4 acc = make_float4(0.f, 0.f, 0.f, 0.f);

#define LD4(OFF) (*(const float4*)(fmb + (OFF)))
#define ACC4(Wt, F) \
        acc.x = fmaf((Wt), (F).x, acc.x); acc.y = fmaf((Wt), (F).y, acc.y); \
        acc.z = fmaf((Wt), (F).z, acc.z); acc.w = fmaf((Wt), (F).w, acc.w);

        const float4 fAA = LD4(rA + cA + cb);
        const float4 fAB = LD4(rA + cB + cb);
        const float4 fBA = LD4(rB + cA + cb);
        const float4 fBB = LD4(rB + cB + cb);
        const float4 fAC = LD4(rA + cC + cb);
        const float4 fAD = LD4(rA + cD + cb);
        const float4 fBC = LD4(rB + cC + cb);
        const float4 fBD = LD4(rB + cD + cb);
        const float4 fCA = LD4(rC + cA + cb);
        const float4 fCB = LD4(rC + cB + cb);
        const float4 fDA = LD4(rD + cA + cb);
        const float4 fDB = LD4(rD + cB + cb);
        const float4 fCC = LD4(rC + cC + cb);
        const float4 fCD = LD4(rC + cD + cb);
        const float4 fDC = LD4(rD + cC + cb);
        const float4 fDD = LD4(rD + cD + cb);

        ACC4(hy0 * hx0, fAA); ACC4(hy0 * lx0, fAB);
        ACC4(ly0 * hx0, fBA); ACC4(ly0 * lx0, fBB);
        ACC4(hy0 * hx1, fAC); ACC4(hy0 * lx1, fAD);
        ACC4(ly0 * hx1, fBC); ACC4(ly0 * lx1, fBD);
        ACC4(hy1 * hx0, fCA); ACC4(hy1 * lx0, fCB);
        ACC4(ly1 * hx0, fDA); ACC4(ly1 * lx0, fDB);
        ACC4(hy1 * hx1, fCC); ACC4(hy1 * lx1, fCD);
        ACC4(ly1 * hx1, fDC); ACC4(ly1 * lx1, fDD);
#undef LD4
#undef ACC4

        *(float4*)&tile[bin * CPAD + (lane << 2)] = make_float4(
            acc.x * 0.25f, acc.y * 0.25f, acc.z * 0.25f, acc.w * 0.25f);
    }

    __syncthreads();

    // ---- writeback: contiguous 256*49 floats, coalesced float4 stores ----
    float* oreg = out + (size_t)roi * (CCH * SS);
    for (int i = t; i < (CCH * SS) / 4; i += 512) {
        const int f0 = i * 4;
        float4 v;
        { const int c = (f0 + 0) / SS, bn = (f0 + 0) - c * SS; v.x = tile[bn * CPAD + c]; }
        { const int c = (f0 + 1) / SS, bn = (f0 + 1) - c * SS; v.y = tile[bn * CPAD + c]; }
        { const int c = (f0 + 2) / SS, bn = (f0 + 2) - c * SS; v.z = tile[bn * CPAD + c]; }
        { const int c = (f0 + 3) / SS, bn = (f0 + 3) - c * SS; v.w = tile[bn * CPAD + c]; }
        *(float4*)(oreg + f0) = v;
    }
}

extern "C" void kernel_launch(void* const* d_in, const int* in_sizes, int n_in,
                              void* d_out, int out_size, void* d_ws, size_t ws_size,
                              hipStream_t stream) {
    const float* fm2  = (const float*)d_in[0];
    const float* fm3  = (const float*)d_in[1];
    const float* fm4  = (const float*)d_in[2];
    const float* fm5  = (const float*)d_in[3];
    const float* rois = (const float*)d_in[4];
    float* out = (float*)d_out;

    roialign_kernel<<<BATCH * NROI, 512, 0, stream>>>(fm2, fm3, fm4, fm5, rois, out);
}